// Round 1
// baseline (203.478 us; speedup 1.0000x reference)
//
#include <hip/hip_runtime.h>

// VQ-VAE loss: B=2, Q=64, K=512, N=1024, C=256, STRIDE=64, Nw=N*64-1=65535
//
// reference = mean_{b,t} [ logsoftmax(quant_pred)[b, tgt[b,t], t]
//                          + 1.25 * min_k sum_q (ze[b,q,t/64] - emb[k,t/64])^2 ]
//
// min_k sum_q (v_q - e)^2 = S2 - 2 e S1 + Q e^2  with S1=sum_q v, S2=sum_q v^2.
//
// Fully fused single kernel: each wave (64 lanes) covers 64 consecutive wav
// positions t that share one bottleneck index n = t>>6, so the VQ min-distance
// for n is computed per-wave in registers (no workspace, no second kernel).
// The class-dim logsumexp streams quant_pred with an 8-deep two-stage load
// pipeline (8 outstanding dwords/wave) to reach HBM BW at 2 waves/SIMD.

#define QQ   64
#define NN   1024
#define KK   512
#define CLS  256
#define NW   65535

__global__ __launch_bounds__(256) void vq_fused_kernel(
        const float* __restrict__ qp,
        const float* __restrict__ ze,
        const float* __restrict__ emb,
        const int*   __restrict__ tgt,
        float* __restrict__ out)
{
    const int g     = blockIdx.x * 256 + threadIdx.x;
    const int b     = g >> 16;          // 65536 positions per batch entry
    const int t     = g & 0xFFFF;
    const bool valid = (t < NW);
    const int tc    = valid ? t : (NW - 1);   // clamp; contribution zeroed below
    const int n     = tc >> 6;          // wave-uniform (64 t's share one n)
    const int lane  = threadIdx.x & 63;

    const float* p = qp + (size_t)b * CLS * NW + tc;

    // ---- issue independent long-latency loads first -----------------------
    int tg = tgt[(size_t)b * NW + tc];

    float cur[8];                        // class group 0 — overlaps phase 1
    #pragma unroll
    for (int u = 0; u < 8; ++u) cur[u] = p[(size_t)u * NW];

    // ---- phase 1: 1.25 * min_k cost for this wave's n (registers only) ----
    float v  = ze[(size_t)(b * QQ + lane) * NN + n];   // lane = q
    float s1 = v, s2 = v * v;
    #pragma unroll
    for (int msk = 32; msk >= 1; msk >>= 1) {
        s1 += __shfl_xor(s1, msk, 64);
        s2 += __shfl_xor(s2, msk, 64);
    }
    float best = 3.4e38f;
    float n2s1 = -2.0f * s1;
    #pragma unroll
    for (int j = 0; j < KK / 64; ++j) {                // lane strided over k
        float e = emb[(size_t)(lane + 64 * j) * NN + n];
        float cost = fmaf(e, fmaf((float)QQ, e, n2s1), s2);
        best = fminf(best, cost);
    }
    #pragma unroll
    for (int msk = 32; msk >= 1; msk >>= 1)
        best = fminf(best, __shfl_xor(best, msk, 64));
    const float l2 = 1.25f * best;       // all lanes hold it

    // target logit: one gather instead of 256 per-element compares; issued
    // here so its latency hides under the whole LSE loop (used only at end).
    float tv = p[(size_t)tg * NW];

    // ---- phase 2: online logsumexp over classes, 8-wide pipelined ---------
    float m = -3.4e38f, s = 0.0f;
    auto merge8 = [&](const float* x) {
        float m01 = fmaxf(x[0], x[1]), m23 = fmaxf(x[2], x[3]);
        float m45 = fmaxf(x[4], x[5]), m67 = fmaxf(x[6], x[7]);
        float m8  = fmaxf(fmaxf(m01, m23), fmaxf(m45, m67));
        float s8  = __expf(x[0] - m8) + __expf(x[1] - m8)
                  + __expf(x[2] - m8) + __expf(x[3] - m8)
                  + __expf(x[4] - m8) + __expf(x[5] - m8)
                  + __expf(x[6] - m8) + __expf(x[7] - m8);
        float nm  = fmaxf(m, m8);
        s = s * __expf(m - nm) + s8 * __expf(m8 - nm);
        m = nm;
    };

    for (int c = 8; c < CLS; c += 8) {
        float nxt[8];
        #pragma unroll
        for (int u = 0; u < 8; ++u) nxt[u] = p[(size_t)(c + u) * NW];
        merge8(cur);                     // compute on prev group while loads fly
        #pragma unroll
        for (int u = 0; u < 8; ++u) cur[u] = nxt[u];
    }
    merge8(cur);                         // final group

    float lse = m + __logf(s);
    float contrib = valid ? (tv - lse + l2) : 0.0f;

    // ---- block reduce + one atomic per block ------------------------------
    #pragma unroll
    for (int msk = 32; msk >= 1; msk >>= 1)
        contrib += __shfl_xor(contrib, msk, 64);

    __shared__ float part[4];
    int wv = threadIdx.x >> 6;
    if (lane == 0) part[wv] = contrib;
    __syncthreads();
    if (threadIdx.x == 0) {
        float blk = part[0] + part[1] + part[2] + part[3];
        atomicAdd(out, blk * (1.0f / 131070.0f));   // mean over B*Nw
    }
}

extern "C" void kernel_launch(void* const* d_in, const int* in_sizes, int n_in,
                              void* d_out, int out_size, void* d_ws, size_t ws_size,
                              hipStream_t stream) {
    const float* quant_pred = (const float*)d_in[0];   // (B, 256, 65535) fp32
    const float* ze         = (const float*)d_in[1];   // (B, 64, 1024)   fp32
    const float* emb        = (const float*)d_in[2];   // (512, 1024)     fp32
    const int*   target     = (const int*)  d_in[3];   // (B, 1, 65535)   int32
    float* out = (float*)d_out;                        // scalar fp32
    (void)d_ws; (void)ws_size; (void)in_sizes; (void)n_in; (void)out_size;

    hipMemsetAsync(out, 0, sizeof(float), stream);
    vq_fused_kernel<<<512, 256, 0, stream>>>(quant_pred, ze, emb, target, out);
}